// Round 10
// baseline (568.243 us; speedup 1.0000x reference)
//
#include <hip/hip_runtime.h>
#include <math.h>

#define CDIM 256
#define LSEQ 8192
#define BATCH 8
#define MTOT (BATCH * LSEQ)
#define PADROWS 8208           // 8 + 8192 + 8 per batch
#define PAD0 8

typedef unsigned short ushort_t;
typedef unsigned int uint_t;

typedef __bf16 bf16x8 __attribute__((ext_vector_type(8)));
typedef float f32x4 __attribute__((ext_vector_type(4)));

__device__ __forceinline__ ushort_t f2bf(float f) {
    union { float f; uint_t u; } v; v.f = f;
    uint_t u = v.u;
    return (ushort_t)((u + 0x7FFFu + ((u >> 16) & 1u)) >> 16);  // RNE
}
__device__ __forceinline__ float bf2f(ushort_t h) {
    union { uint_t u; float f; } v; v.u = ((uint_t)h) << 16;
    return v.f;
}
__device__ __forceinline__ float gelu_exact(float x) {
    return 0.5f * x * (1.0f + erff(x * 0.70710678118654752440f));
}

// async global(16B/lane) -> LDS (wave-uniform base + lane*16)
__device__ __forceinline__ void gload16(const ushort_t* g, ushort_t* lds) {
    __builtin_amdgcn_global_load_lds(
        reinterpret_cast<__attribute__((address_space(1))) uint_t*>(
            reinterpret_cast<uintptr_t>(g)),
        reinterpret_cast<__attribute__((address_space(3))) uint_t*>(
            reinterpret_cast<uintptr_t>(lds)),
        16, 0, 0);
}

// ---------------- fp32 -> bf16 convert ----------------
__global__ __launch_bounds__(256) void cvt_f32_bf16(const float* __restrict__ in,
                                                    ushort_t* __restrict__ out) {
    int i = blockIdx.x * 256 + threadIdx.x;
    float4 v = ((const float4*)in)[i];
    ushort4 o = { f2bf(v.x), f2bf(v.y), f2bf(v.z), f2bf(v.w) };
    ((ushort4*)out)[i] = o;
}

// ---------------- transpose + convert: out[n*K+k] = bf16(in[k*ldin+col0+n]) ----------------
__global__ __launch_bounds__(256) void transpose_cvt(const float* __restrict__ in,
                                                     ushort_t* __restrict__ out,
                                                     int K, int N, int ldin, int col0) {
    __shared__ float t[32][33];
    int k0 = blockIdx.x * 32, n0 = blockIdx.y * 32;
    int tx = threadIdx.x, ty = threadIdx.y;   // (32,8)
    #pragma unroll
    for (int i = 0; i < 4; i++) {
        int k = k0 + ty + i * 8;
        t[ty + i * 8][tx] = in[(size_t)k * ldin + col0 + n0 + tx];
    }
    __syncthreads();
    #pragma unroll
    for (int i = 0; i < 4; i++) {
        int n = n0 + ty + i * 8;
        out[(size_t)n * K + k0 + tx] = f2bf(t[tx][ty + i * 8]);
    }
}

// ---------------- zero the guard bands of a ctx_pad buffer ----------------
__global__ __launch_bounds__(256) void zero_guards(ushort_t* __restrict__ ctx_pad) {
    int i = blockIdx.x * 256 + threadIdx.x;   // 8*16*256 = 32768
    int c = i & 255;
    int r = (i >> 8) & 15;
    int b = i >> 12;
    int row = b * PADROWS + ((r < 8) ? r : (PADROWS - 16 + r));
    ctx_pad[(size_t)row * CDIM + c] = 0;
}

// ---------------- generic MFMA GEMM (m97 structure): 128x128 tile ----------------
// MODE 0: C[row*256+col] = acc + bias  (fp32 out)
// MODE 1: fea: col<256 -> q_bf(bf16) ; col>=256 -> ctx_pad (padded rows, bf16)
// MODE 2: qc in-place: q_out[idx] = bf16(bf2f(q_out[idx]) * (acc+bias))
template <int MODE>
__global__ __launch_bounds__(256) void gemm_bf16(
    const ushort_t* __restrict__ A, const ushort_t* __restrict__ BT,
    const float* __restrict__ bias,
    float* __restrict__ C, ushort_t* __restrict__ q_out, ushort_t* __restrict__ ctx_pad,
    int Ktot)
{
    __shared__ __align__(16) ushort_t As[128 * 32];
    __shared__ __align__(16) ushort_t Bs[128 * 32];
    int tid = threadIdx.x;
    int w = tid >> 6, l = tid & 63;
    int bn = blockIdx.x * 128;
    int by = blockIdx.y;
    long arow0 = (long)by * 128;
    int crow0 = by * 128;

    int wr = w >> 1, wc = w & 1;
    int lr = l & 15, lk = (l >> 4) * 8;
    int sr = l >> 2;
    int sc = (l & 3) * 8;

    f32x4 acc[4][4] = {};

    int nsteps = Ktot >> 5;
    for (int kt = 0; kt < nsteps; ++kt) {
        int k0 = kt << 5;
        #pragma unroll
        for (int jj = 0; jj < 2; ++jj) {
            int j = w * 2 + jj;
            int r = j * 16 + sr;
            gload16(A + (arow0 + r) * CDIM + (k0 + sc), &As[j * 512]);
            gload16(BT + (long)(bn + r) * Ktot + (k0 + sc), &Bs[j * 512]);
        }
        __syncthreads();
        bf16x8 av[4], bv[4];
        #pragma unroll
        for (int m = 0; m < 4; ++m)
            av[m] = *reinterpret_cast<const bf16x8*>(&As[(wr * 64 + m * 16 + lr) * 32 + lk]);
        #pragma unroll
        for (int n = 0; n < 4; ++n)
            bv[n] = *reinterpret_cast<const bf16x8*>(&Bs[(wc * 64 + n * 16 + lr) * 32 + lk]);
        #pragma unroll
        for (int m = 0; m < 4; ++m)
            #pragma unroll
            for (int n = 0; n < 4; ++n)
                acc[m][n] = __builtin_amdgcn_mfma_f32_16x16x32_bf16(av[m], bv[n], acc[m][n], 0, 0, 0);
        __syncthreads();
    }

    int rbase = (l >> 4) * 4;
    #pragma unroll
    for (int n = 0; n < 4; ++n) {
        int col = bn + wc * 64 + n * 16 + lr;
        float bia = bias[col];
        #pragma unroll
        for (int m = 0; m < 4; ++m) {
            int rowb = crow0 + wr * 64 + m * 16 + rbase;
            #pragma unroll
            for (int r = 0; r < 4; ++r) {
                float v = acc[m][n][r] + bia;
                int row = rowb + r;
                if (MODE == 0) {
                    C[(size_t)row * CDIM + col] = v;
                } else if (MODE == 1) {
                    if (col < CDIM) {
                        q_out[(size_t)row * CDIM + col] = f2bf(v);
                    } else {
                        int bb = row >> 13, tb = row & (LSEQ - 1);
                        ctx_pad[((size_t)bb * PADROWS + PAD0 + tb) * CDIM + (col - CDIM)] = f2bf(v);
                    }
                } else {
                    size_t idx = (size_t)row * CDIM + col;
                    q_out[idx] = f2bf(bf2f(q_out[idx]) * v);
                }
            }
        }
    }
}

// ---------------- 8-phase fused conv: BM=BN=256, 512 thr, 4 LDS slots ----------------
// Flat-GEMM view over padded ctx (Ktot = KW*256, koff = -P*256). Per-wave output
// 128x64 (acc[8][4]). K-tile = 32. Phases per 2-tile iter:
//   {8 ds_read || 2 gload_lds ; barrier ; setprio(1) ; 16 MFMA ; setprio(0) ;
//    [vmcnt(4) at phases 1,3] ; barrier}
// Slot rotation verified: tile T staged >=1.5 iters before consumption; vmcnt(4)
// retires each stage group before its consumer's barrier crossing.
// Epilogue: bias + GELU + in-block LN (256 full cols) -> ctx_out (bf16, padded).
__global__ __launch_bounds__(512, 2) void conv_fused(
    const ushort_t* __restrict__ A, const ushort_t* __restrict__ BT,
    const float* __restrict__ bias,
    const float* __restrict__ lng, const float* __restrict__ lnb,
    ushort_t* __restrict__ ctx_out, int KW, int Ktot)
{
    __shared__ __align__(16) ushort_t As[4][256 * 32];  // 4 x 16KB
    __shared__ __align__(16) ushort_t Bs[4][256 * 32];  // 4 x 16KB  -> 128KB

    int tid = threadIdx.x;
    int w = tid >> 6, l = tid & 63;
    int by = blockIdx.x;              // 256 blocks: 32 tiles/batch
    int b = by >> 5;
    int tloc = (by & 31) << 8;
    int P = KW >> 1;
    const ushort_t* Abase = A + ((size_t)b * PADROWS + PAD0 + tloc) * CDIM - P * 256;

    int wr128 = (w >> 2) * 128;       // 0 / 128
    int wc64 = (w & 3) * 64;          // 0..192
    int lr = l & 15;
    int quad = l >> 4;

    f32x4 acc[8][4] = {};

    // stage 2 load-groups (16B/lane each) of tile T: jlo in {0,2}
    auto stage2 = [&](int T, int jlo) {
        #pragma unroll
        for (int jj = 0; jj < 2; ++jj) {
            int o = (jlo + jj) * 512 + tid;
            if (o < 1024) {                       // A: 256 rows x 4 chunks
                int row = o >> 2, cp = o & 3;
                int cg = cp ^ ((row >> 1) & 3);   // proven-0-conflict swizzle
                gload16(Abase + (size_t)row * CDIM + T * 32 + cg * 8,
                        &As[T & 3][(size_t)(o & ~63) * 8]);
            } else {                              // B: 256 rows x 4 chunks
                int ob = o - 1024;
                int n = ob >> 2, cp = ob & 3;
                int cg = cp ^ ((n >> 1) & 3);
                gload16(BT + (size_t)n * Ktot + T * 32 + cg * 8,
                        &Bs[T & 3][(size_t)(ob & ~63) * 8]);
            }
        }
    };

#define CONV_PHASE(TT, H, STT, JLO, DOSTAGE, VM) do {                          \
    const ushort_t* as_ = &As[(TT) & 3][0];                                    \
    const ushort_t* bs_ = &Bs[(TT) & 3][0];                                    \
    bf16x8 av[4], bv[4];                                                       \
    _Pragma("unroll")                                                          \
    for (int mi = 0; mi < 4; ++mi) {                                           \
        int row = wr128 + ((H) * 4 + mi) * 16 + lr;                            \
        int pc = quad ^ ((row >> 1) & 3);                                      \
        av[mi] = *reinterpret_cast<const bf16x8*>(&as_[row * 32 + pc * 8]);    \
    }                                                                          \
    _Pragma("unroll")                                                          \
    for (int n = 0; n < 4; ++n) {                                              \
        int nr = wc64 + n * 16 + lr;                                           \
        int pc = quad ^ ((nr >> 1) & 3);                                       \
        bv[n] = *reinterpret_cast<const bf16x8*>(&bs_[nr * 32 + pc * 8]);      \
    }                                                                          \
    if (DOSTAGE) stage2(STT, JLO);                                             \
    __builtin_amdgcn_s_barrier();                                              \
    __builtin_amdgcn_s_setprio(1);                                             \
    _Pragma("unroll")                                                          \
    for (int mi = 0; mi < 4; ++mi)                                             \
        _Pragma("unroll")                                                      \
        for (int n = 0; n < 4; ++n)                                            \
            acc[(H) * 4 + mi][n] = __builtin_amdgcn_mfma_f32_16x16x32_bf16(    \
                av[mi], bv[n], acc[(H) * 4 + mi][n], 0, 0, 0);                 \
    __builtin_amdgcn_s_setprio(0);                                             \
    if (VM) asm volatile("s_waitcnt vmcnt(4)" ::: "memory");                   \
    __builtin_amdgcn_s_barrier();                                              \
} while (0)

    // prologue: tiles 0,1,2 staged, full drain
    stage2(0, 0); stage2(0, 2);
    stage2(1, 0); stage2(1, 2);
    stage2(2, 0); stage2(2, 2);
    __syncthreads();

    int nt = Ktot >> 5;               // 24 / 40 / 56
    int niter = nt >> 1;
    for (int i = 0; i < niter; ++i) {
        int t0 = 2 * i;
        bool s0 = (t0 + 3) < nt;      // stage tile t0+3 in phases 0-1
        bool s1 = (t0 + 4) < nt;      // stage tile t0+4 in phases 2-3
        CONV_PHASE(t0,     0, t0 + 3, 0, s0, false);
        CONV_PHASE(t0,     1, t0 + 3, 2, s0, true);
        CONV_PHASE(t0 + 1, 0, t0 + 4, 0, s1, false);
        CONV_PHASE(t0 + 1, 1, t0 + 4, 2, s1, true);
    }
    asm volatile("s_waitcnt vmcnt(0)" ::: "memory");
    __builtin_amdgcn_s_barrier();
#undef CONV_PHASE

    // ---- epilogue: bias + GELU + LN (full 256 cols in block) ----
    float* rs = (float*)&As[0][0];        // [256][4]
    float* rq = rs + 1024;                // [256][4]
    float bias_c[4], lng_c[4], lnb_c[4];
    #pragma unroll
    for (int n = 0; n < 4; ++n) {
        int col = wc64 + n * 16 + lr;
        bias_c[n] = bias[col];
        lng_c[n] = lng[col];
        lnb_c[n] = lnb[col];
    }
    #pragma unroll
    for (int m = 0; m < 8; ++m) {
        #pragma unroll
        for (int r = 0; r < 4; ++r) {
            float s = 0.0f, sq = 0.0f;
            #pragma unroll
            for (int n = 0; n < 4; ++n) {
                float v = acc[m][n][r] + bias_c[n];
                v = gelu_exact(v);
                acc[m][n][r] = v;
                s += v; sq += v * v;
            }
            s += __shfl_xor(s, 1);  sq += __shfl_xor(sq, 1);
            s += __shfl_xor(s, 2);  sq += __shfl_xor(sq, 2);
            s += __shfl_xor(s, 4);  sq += __shfl_xor(sq, 4);
            s += __shfl_xor(s, 8);  sq += __shfl_xor(sq, 8);
            if (lr == 0) {
                int row = wr128 + m * 16 + quad * 4 + r;
                rs[row * 4 + (w & 3)] = s;
                rq[row * 4 + (w & 3)] = sq;
            }
        }
    }
    __syncthreads();
    #pragma unroll
    for (int m = 0; m < 8; ++m) {
        #pragma unroll
        for (int r = 0; r < 4; ++r) {
            int row = wr128 + m * 16 + quad * 4 + r;
            float mean = (rs[row * 4] + rs[row * 4 + 1] + rs[row * 4 + 2] + rs[row * 4 + 3]) * (1.0f / 256.0f);
            float var  = (rq[row * 4] + rq[row * 4 + 1] + rq[row * 4 + 2] + rq[row * 4 + 3]) * (1.0f / 256.0f) - mean * mean;
            float inv = rsqrtf(var + 1e-3f);
            ushort_t* cp = ctx_out + ((size_t)b * PADROWS + PAD0 + tloc + row) * CDIM;
            #pragma unroll
            for (int n = 0; n < 4; ++n) {
                int col = wc64 + n * 16 + lr;
                float y = (acc[m][n][r] - mean) * inv * lng_c[n] + lnb_c[n];
                cp[col] = f2bf(y);
            }
        }
    }
}

// ---------------- gates sliver ----------------
__global__ __launch_bounds__(256) void gates_kernel(const float* __restrict__ x,
                                                    const float* __restrict__ f_w,
                                                    const float* __restrict__ f_b,
                                                    float* __restrict__ gates) {
    __shared__ float fcol[256][4];
    int tid = threadIdx.x;
    #pragma unroll
    for (int j = 0; j < 4; ++j) fcol[tid][j] = f_w[(size_t)tid * 516 + 512 + j];
    __syncthreads();
    int w = tid >> 6, l = tid & 63;
    int t = blockIdx.x * 4 + w;
    float4 xv = ((const float4*)(x + (size_t)t * CDIM))[l];
    int c = l * 4;
    float a[4];
    #pragma unroll
    for (int j = 0; j < 4; ++j)
        a[j] = xv.x * fcol[c][j] + xv.y * fcol[c + 1][j] + xv.z * fcol[c + 2][j] + xv.w * fcol[c + 3][j];
    #pragma unroll
    for (int off = 32; off >= 1; off >>= 1)
        #pragma unroll
        for (int j = 0; j < 4; ++j) a[j] += __shfl_xor(a[j], off);
    if (l == 0) {
        #pragma unroll
        for (int j = 0; j < 4; ++j) gates[(size_t)t * 4 + j] = a[j] + f_b[512 + j];
    }
}

// ---------------- column mean over L (two stage), input bf16 padded ----------------
__global__ __launch_bounds__(256) void col_mean_partial(const ushort_t* __restrict__ ctx_pad,
                                                        float* __restrict__ partial) {
    int b = blockIdx.x, chunk = blockIdx.y, c = threadIdx.x;
    const ushort_t* base = ctx_pad + ((size_t)b * PADROWS + PAD0 + chunk * 256) * CDIM + c;
    float s = 0.0f;
    for (int r = 0; r < 256; ++r) s += bf2f(base[(size_t)r * CDIM]);
    partial[((size_t)b * 32 + chunk) * CDIM + c] = s;
}

__global__ __launch_bounds__(256) void col_mean_final(const float* __restrict__ partial,
                                                      float* __restrict__ meanv) {
    int b = blockIdx.x, c = threadIdx.x;
    float s = 0.0f;
    for (int i = 0; i < 32; ++i) s += partial[((size_t)b * 32 + i) * CDIM + c];
    meanv[b * CDIM + c] = s * (1.0f / (float)LSEQ);
}

// ---------------- A_bf = bf16(sum_l gate_l*ctx_l + meanv*g3) ----------------
__global__ __launch_bounds__(256) void finalize_A(
    const ushort_t* __restrict__ c0buf, const ushort_t* __restrict__ c1buf,
    const ushort_t* __restrict__ c2buf,
    const float* __restrict__ meanv, const float* __restrict__ gates,
    ushort_t* __restrict__ A_bf)
{
    int i = blockIdx.x * 256 + threadIdx.x;   // 8 channels per thread
    int t = i >> 5;
    int c8 = (i & 31) * 8;
    int b = t >> 13, tb = t & (LSEQ - 1);
    size_t pidx = ((size_t)b * PADROWS + PAD0 + tb) * CDIM + c8;
    const float* g = gates + (size_t)t * 4;
    float g0 = g[0], g1 = g[1], g2 = g[2], g3 = g[3];
    ushort4 a0 = *(const ushort4*)(c0buf + pidx);
    ushort4 a1 = *(const ushort4*)(c0buf + pidx + 4);
    ushort4 b0 = *(const ushort4*)(c1buf + pidx);
    ushort4 b1 = *(const ushort4*)(c1buf + pidx + 4);
    ushort4 d0 = *(const ushort4*)(c2buf + pidx);
    ushort4 d1 = *(const ushort4*)(c2buf + pidx + 4);
    const float* mv = meanv + b * CDIM + c8;
    ushort_t out[8];
    ushort_t va[8] = { a0.x, a0.y, a0.z, a0.w, a1.x, a1.y, a1.z, a1.w };
    ushort_t vb[8] = { b0.x, b0.y, b0.z, b0.w, b1.x, b1.y, b1.z, b1.w };
    ushort_t vd[8] = { d0.x, d0.y, d0.z, d0.w, d1.x, d1.y, d1.z, d1.w };
    #pragma unroll
    for (int j = 0; j < 8; ++j) {
        float v = bf2f(va[j]) * g0 + bf2f(vb[j]) * g1 + bf2f(vd[j]) * g2 + mv[j] * g3;
        out[j] = f2bf(v);
    }
    *(ushort4*)(A_bf + (size_t)t * CDIM + c8)     = make_ushort4(out[0], out[1], out[2], out[3]);
    *(ushort4*)(A_bf + (size_t)t * CDIM + c8 + 4) = make_ushort4(out[4], out[5], out[6], out[7]);
}

extern "C" void kernel_launch(void* const* d_in, const int* in_sizes, int n_in,
                              void* d_out, int out_size, void* d_ws, size_t ws_size,
                              hipStream_t stream) {
    const float* x      = (const float*)d_in[0];
    const float* f_w    = (const float*)d_in[1];
    const float* f_b    = (const float*)d_in[2];
    const float* h_w    = (const float*)d_in[3];
    const float* h_b    = (const float*)d_in[4];
    const float* proj_w = (const float*)d_in[5];
    const float* proj_b = (const float*)d_in[6];
    const float* conv_w[3] = { (const float*)d_in[7],  (const float*)d_in[11], (const float*)d_in[15] };
    const float* conv_b[3] = { (const float*)d_in[8],  (const float*)d_in[12], (const float*)d_in[16] };
    const float* ln_g[3]   = { (const float*)d_in[9],  (const float*)d_in[13], (const float*)d_in[17] };
    const float* ln_b[3]   = { (const float*)d_in[10], (const float*)d_in[14], (const float*)d_in[18] };

    const size_t MC = (size_t)MTOT * CDIM;
    const size_t PADC = (size_t)BATCH * PADROWS * CDIM;
    char* w = (char*)d_ws;
    ushort_t* x_bf  = (ushort_t*)w;  w += MC * 2;
    ushort_t* q_bf  = (ushort_t*)w;  w += MC * 2;
    ushort_t* ctxF  = (ushort_t*)w;  w += PADC * 2;
    ushort_t* ctx0  = (ushort_t*)w;  w += PADC * 2;
    ushort_t* ctx1  = (ushort_t*)w;  w += PADC * 2;
    ushort_t* ctx2  = (ushort_t*)w;  w += PADC * 2;
    float* gates    = (float*)w;     w += (size_t)MTOT * 4 * 4;
    float* partial  = (float*)w;     w += (size_t)8 * 32 * CDIM * 4;
    float* meanv    = (float*)w;     w += (size_t)8 * CDIM * 4;
    ushort_t* f_wT  = (ushort_t*)w;  w += (size_t)512 * 256 * 2;
    ushort_t* convT0 = (ushort_t*)w; w += (size_t)768 * 256 * 2;
    ushort_t* convT1 = (ushort_t*)w; w += (size_t)1280 * 256 * 2;
    ushort_t* convT2 = (ushort_t*)w; w += (size_t)1792 * 256 * 2;
    ushort_t* h_wT   = (ushort_t*)w; w += (size_t)256 * 256 * 2;
    ushort_t* proj_wT = (ushort_t*)w; w += (size_t)256 * 256 * 2;
    ushort_t* A_bf = x_bf;           // reuse (x_bf consumed after fea gemm)

    dim3 blk(256);
    dim3 t8(32, 8);

    // weight prep + x conversion
    cvt_f32_bf16<<<dim3(MC / 4 / 256), blk, 0, stream>>>(x, x_bf);
    transpose_cvt<<<dim3(8, 16), t8, 0, stream>>>(f_w, f_wT, 256, 512, 516, 0);
    transpose_cvt<<<dim3(24, 8), t8, 0, stream>>>(conv_w[0], convT0, 768, 256, 256, 0);
    transpose_cvt<<<dim3(40, 8), t8, 0, stream>>>(conv_w[1], convT1, 1280, 256, 256, 0);
    transpose_cvt<<<dim3(56, 8), t8, 0, stream>>>(conv_w[2], convT2, 1792, 256, 256, 0);
    transpose_cvt<<<dim3(8, 8), t8, 0, stream>>>(h_w, h_wT, 256, 256, 256, 0);
    transpose_cvt<<<dim3(8, 8), t8, 0, stream>>>(proj_w, proj_wT, 256, 256, 256, 0);
    zero_guards<<<dim3(128), blk, 0, stream>>>(ctxF);
    zero_guards<<<dim3(128), blk, 0, stream>>>(ctx0);
    zero_guards<<<dim3(128), blk, 0, stream>>>(ctx1);
    zero_guards<<<dim3(128), blk, 0, stream>>>(ctx2);

    // feature GEMM (q + ctx) and gates sliver
    gemm_bf16<1><<<dim3(4, 512), blk, 0, stream>>>(x_bf, f_wT, f_b,
        nullptr, q_bf, ctxF, 256);
    gates_kernel<<<dim3(MTOT / 4), blk, 0, stream>>>(x, f_w, f_b, gates);

    // three 8-phase fused conv+GELU+LN levels (256x256 tiles, 256 blocks)
    conv_fused<<<dim3(256), dim3(512), 0, stream>>>(ctxF, convT0, conv_b[0],
        ln_g[0], ln_b[0], ctx0, 3, 768);
    conv_fused<<<dim3(256), dim3(512), 0, stream>>>(ctx0, convT1, conv_b[1],
        ln_g[1], ln_b[1], ctx1, 5, 1280);
    conv_fused<<<dim3(256), dim3(512), 0, stream>>>(ctx1, convT2, conv_b[2],
        ln_g[2], ln_b[2], ctx2, 7, 1792);

    // global context mean (final ctx is ctx2)
    col_mean_partial<<<dim3(BATCH, 32), blk, 0, stream>>>(ctx2, partial);
    col_mean_final<<<dim3(BATCH), blk, 0, stream>>>(partial, meanv);

    // combine levels: A_bf = bf16(sum gate_l*ctx_l + mean*g3)
    finalize_A<<<dim3(MTOT * 32 / 256), blk, 0, stream>>>(ctx0, ctx1, ctx2,
        meanv, gates, A_bf);

    // h GEMM with fused q .* (.) epilogue: q_bf <- bf16(q_bf * ctxh)
    gemm_bf16<2><<<dim3(2, 512), blk, 0, stream>>>(A_bf, h_wT, h_b,
        nullptr, q_bf, nullptr, 256);
    // final projection: qc @ proj_w -> d_out (fp32)
    gemm_bf16<0><<<dim3(2, 512), blk, 0, stream>>>(q_bf, proj_wT, proj_b,
        (float*)d_out, nullptr, nullptr, 256);
}

// Round 11
// 373.899 us; speedup vs baseline: 1.5198x; 1.5198x over previous
//
#include <hip/hip_runtime.h>
#include <math.h>

#define CDIM 256
#define LSEQ 8192
#define BATCH 8
#define MTOT (BATCH * LSEQ)
#define PADROWS 8208           // 8 + 8192 + 8 per batch
#define PAD0 8

typedef unsigned short ushort_t;
typedef unsigned int uint_t;

typedef __bf16 bf16x8 __attribute__((ext_vector_type(8)));
typedef float f32x4 __attribute__((ext_vector_type(4)));

__device__ __forceinline__ ushort_t f2bf(float f) {
    union { float f; uint_t u; } v; v.f = f;
    uint_t u = v.u;
    return (ushort_t)((u + 0x7FFFu + ((u >> 16) & 1u)) >> 16);  // RNE
}
__device__ __forceinline__ float bf2f(ushort_t h) {
    union { uint_t u; float f; } v; v.u = ((uint_t)h) << 16;
    return v.f;
}
__device__ __forceinline__ float gelu_exact(float x) {
    return 0.5f * x * (1.0f + erff(x * 0.70710678118654752440f));
}

// async global(16B/lane) -> LDS (wave-uniform base + lane*16)
__device__ __forceinline__ void gload16(const ushort_t* g, ushort_t* lds) {
    __builtin_amdgcn_global_load_lds(
        reinterpret_cast<__attribute__((address_space(1))) uint_t*>(
            reinterpret_cast<uintptr_t>(g)),
        reinterpret_cast<__attribute__((address_space(3))) uint_t*>(
            reinterpret_cast<uintptr_t>(lds)),
        16, 0, 0);
}

// ---------------- fused x: bf16 convert + gates sliver ----------------
// block = 4 rows of x (256 thr, wave per row). Writes x_bf and gates.
__global__ __launch_bounds__(256) void cvt_gates(
    const float* __restrict__ x, const float* __restrict__ f_w,
    const float* __restrict__ f_b,
    ushort_t* __restrict__ x_bf, float* __restrict__ gates)
{
    __shared__ float fcol[256][4];
    int tid = threadIdx.x;
    #pragma unroll
    for (int j = 0; j < 4; ++j) fcol[tid][j] = f_w[(size_t)tid * 516 + 512 + j];
    __syncthreads();
    int w = tid >> 6, l = tid & 63;
    size_t t = (size_t)blockIdx.x * 4 + w;
    float4 xv = ((const float4*)(x + t * CDIM))[l];
    ((ushort4*)(x_bf + t * CDIM))[l] =
        make_ushort4(f2bf(xv.x), f2bf(xv.y), f2bf(xv.z), f2bf(xv.w));
    int c = l * 4;
    float a[4];
    #pragma unroll
    for (int j = 0; j < 4; ++j)
        a[j] = xv.x * fcol[c][j] + xv.y * fcol[c + 1][j] + xv.z * fcol[c + 2][j] + xv.w * fcol[c + 3][j];
    #pragma unroll
    for (int off = 32; off >= 1; off >>= 1)
        #pragma unroll
        for (int j = 0; j < 4; ++j) a[j] += __shfl_xor(a[j], off);
    if (l == 0) {
        #pragma unroll
        for (int j = 0; j < 4; ++j) gates[t * 4 + j] = a[j] + f_b[512 + j];
    }
}

// ---------------- single-launch weight prep: transpose+cvt all 6 weights ----------------
// out[n*K+k] = bf16(in[k*ldin+n]). One 32x32 tile per block; bid ranges per weight.
__global__ __launch_bounds__(256) void prep_weights(
    const float* __restrict__ f_w,  const float* __restrict__ c0,
    const float* __restrict__ c1,   const float* __restrict__ c2,
    const float* __restrict__ h_w,  const float* __restrict__ p_w,
    ushort_t* __restrict__ f_wT, ushort_t* __restrict__ c0T,
    ushort_t* __restrict__ c1T,  ushort_t* __restrict__ c2T,
    ushort_t* __restrict__ h_wT, ushort_t* __restrict__ p_wT)
{
    __shared__ float t[32][33];
    int r = blockIdx.x;
    const float* in; ushort_t* out; int Kt, ldin;
    if (r < 128)              { in = f_w; out = f_wT; Kt = 8;  ldin = 516; }
    else if ((r -= 128) < 192){ in = c0;  out = c0T;  Kt = 24; ldin = 256; }
    else if ((r -= 192) < 320){ in = c1;  out = c1T;  Kt = 40; ldin = 256; }
    else if ((r -= 320) < 448){ in = c2;  out = c2T;  Kt = 56; ldin = 256; }
    else if ((r -= 448) < 64) { in = h_w; out = h_wT; Kt = 8;  ldin = 256; }
    else                      { r -= 64; in = p_w; out = p_wT; Kt = 8; ldin = 256; }
    int K = Kt * 32;
    int k0 = (r % Kt) * 32, n0 = (r / Kt) * 32;
    int tx = threadIdx.x & 31, ty = threadIdx.x >> 5;   // (32,8)
    #pragma unroll
    for (int i = 0; i < 4; i++) {
        int k = k0 + ty + i * 8;
        t[ty + i * 8][tx] = in[(size_t)k * ldin + n0 + tx];
    }
    __syncthreads();
    #pragma unroll
    for (int i = 0; i < 4; i++) {
        int n = n0 + ty + i * 8;
        out[(size_t)n * K + k0 + tx] = f2bf(t[tx][ty + i * 8]);
    }
}

// ---------------- zero guard bands of 4 contiguous ctx_pad buffers ----------------
__global__ __launch_bounds__(256) void zero_guards_all(ushort_t* __restrict__ ctx_base) {
    int i = blockIdx.x * 256 + threadIdx.x;   // 4 * 8*16*256 = 131072
    int buf = i >> 15;
    int j = i & 32767;
    int c = j & 255;
    int rr = (j >> 8) & 15;
    int b = j >> 12;
    size_t row = (size_t)b * PADROWS + ((rr < 8) ? rr : (PADROWS - 16 + rr));
    ctx_base[((size_t)buf * BATCH * PADROWS + row) * CDIM + c] = 0;
}

// ---------------- generic MFMA GEMM (m97 structure): 128x128 tile ----------------
// MODE 0: C[row*256+col] = acc + bias  (fp32 out)
// MODE 1: fea: col<256 -> q_bf(bf16) ; col>=256 -> ctx_pad (padded rows, bf16)
// MODE 2: qc in-place: q_out[idx] = bf16(bf2f(q_out[idx]) * (acc+bias))
template <int MODE>
__global__ __launch_bounds__(256) void gemm_bf16(
    const ushort_t* __restrict__ A, const ushort_t* __restrict__ BT,
    const float* __restrict__ bias,
    float* __restrict__ C, ushort_t* __restrict__ q_out, ushort_t* __restrict__ ctx_pad,
    int Ktot)
{
    __shared__ __align__(16) ushort_t As[128 * 32];
    __shared__ __align__(16) ushort_t Bs[128 * 32];
    int tid = threadIdx.x;
    int w = tid >> 6, l = tid & 63;
    int bn = blockIdx.x * 128;
    int by = blockIdx.y;
    long arow0 = (long)by * 128;
    int crow0 = by * 128;

    int wr = w >> 1, wc = w & 1;
    int lr = l & 15, lk = (l >> 4) * 8;
    int sr = l >> 2;
    int sc = (l & 3) * 8;

    f32x4 acc[4][4] = {};

    int nsteps = Ktot >> 5;
    for (int kt = 0; kt < nsteps; ++kt) {
        int k0 = kt << 5;
        #pragma unroll
        for (int jj = 0; jj < 2; ++jj) {
            int j = w * 2 + jj;
            int r = j * 16 + sr;
            gload16(A + (arow0 + r) * CDIM + (k0 + sc), &As[j * 512]);
            gload16(BT + (long)(bn + r) * Ktot + (k0 + sc), &Bs[j * 512]);
        }
        __syncthreads();
        bf16x8 av[4], bv[4];
        #pragma unroll
        for (int m = 0; m < 4; ++m)
            av[m] = *reinterpret_cast<const bf16x8*>(&As[(wr * 64 + m * 16 + lr) * 32 + lk]);
        #pragma unroll
        for (int n = 0; n < 4; ++n)
            bv[n] = *reinterpret_cast<const bf16x8*>(&Bs[(wc * 64 + n * 16 + lr) * 32 + lk]);
        #pragma unroll
        for (int m = 0; m < 4; ++m)
            #pragma unroll
            for (int n = 0; n < 4; ++n)
                acc[m][n] = __builtin_amdgcn_mfma_f32_16x16x32_bf16(av[m], bv[n], acc[m][n], 0, 0, 0);
        __syncthreads();
    }

    int rbase = (l >> 4) * 4;
    #pragma unroll
    for (int n = 0; n < 4; ++n) {
        int col = bn + wc * 64 + n * 16 + lr;
        float bia = bias[col];
        #pragma unroll
        for (int m = 0; m < 4; ++m) {
            int rowb = crow0 + wr * 64 + m * 16 + rbase;
            #pragma unroll
            for (int r = 0; r < 4; ++r) {
                float v = acc[m][n][r] + bia;
                int row = rowb + r;
                if (MODE == 0) {
                    C[(size_t)row * CDIM + col] = v;
                } else if (MODE == 1) {
                    if (col < CDIM) {
                        q_out[(size_t)row * CDIM + col] = f2bf(v);
                    } else {
                        int bb = row >> 13, tb = row & (LSEQ - 1);
                        ctx_pad[((size_t)bb * PADROWS + PAD0 + tb) * CDIM + (col - CDIM)] = f2bf(v);
                    }
                } else {
                    size_t idx = (size_t)row * CDIM + col;
                    q_out[idx] = f2bf(bf2f(q_out[idx]) * v);
                }
            }
        }
    }
}

// ---- staging helpers for conv_fused (BM=128, 512 thr) ----
// A chunk: 144 rows x 32 ch. Source pre-swizzle cg = cp ^ ((row>>1)&3)
// (row stride 64B -> bank period 2 rows; verified 0 conflicts in R7).
__device__ __forceinline__ void stageA128(const ushort_t* Arow0, int cc,
                                          ushort_t* asb, int tid, int w) {
    int row = tid >> 2, cp = tid & 3;
    int cg = cp ^ ((row >> 1) & 3);
    gload16(Arow0 + (size_t)row * CDIM + cc * 32 + cg * 8, asb + (size_t)(w * 64) * 8);
    if (tid < 64) {
        int o2 = 512 + tid;
        int row2 = o2 >> 2, cp2 = o2 & 3;
        int cg2 = cp2 ^ ((row2 >> 1) & 3);
        gload16(Arow0 + (size_t)row2 * CDIM + cc * 32 + cg2 * 8, asb + (size_t)512 * 8);
    }
}
// B chunk: 256 rows x 32 ch, source pre-swizzle cg = cp ^ ((n>>1)&3)
__device__ __forceinline__ void stageB128(const ushort_t* BT, int Ktot, int koffB,
                                          ushort_t* bsb, int tid) {
    #pragma unroll
    for (int i = 0; i < 2; ++i) {
        int o = tid + i * 512;
        int n = o >> 2, cp = o & 3;
        int cg = cp ^ ((n >> 1) & 3);
        gload16(BT + (size_t)n * Ktot + koffB + cg * 8,
                bsb + (size_t)((o >> 6) * 64) * 8);
    }
}

// ---------------- fused conv: BM=128, BN=256, 512 thr, 2 blocks/CU ----------------
// Best verified structure (R5 geometry + R7 corrected swizzle): A chunk dbuf
// (18KB) + B chunk dbuf (32KB) = 51200 B LDS, plain 2-phase loop.
// Epilogue: bias + GELU + LN -> ctx_out (bf16 padded). Stats overlay Bs[0].
__global__ __launch_bounds__(512, 4) void conv_fused(
    const ushort_t* __restrict__ A, const ushort_t* __restrict__ BT,
    const float* __restrict__ bias,
    const float* __restrict__ lng, const float* __restrict__ lnb,
    ushort_t* __restrict__ ctx_out, int KW, int Ktot)
{
    __shared__ __align__(16) ushort_t As2[2][144 * 32];  // 18432 B
    __shared__ __align__(16) ushort_t Bs[2][256 * 32];   // 32768 B

    int tid = threadIdx.x;
    int w = tid >> 6, l = tid & 63;
    int by = blockIdx.x;              // 512 blocks: 64 tiles/batch
    int b = by >> 6;
    int tloc = (by & 63) << 7;
    const ushort_t* Arow0 = A + ((size_t)b * PADROWS + PAD0 + tloc - 8) * CDIM;

    int wr = w >> 2;                  // 0..1 : rows wr*64..+63
    int wc = w & 3;                   // 0..3 : cols wc*64..+63
    int lr = l & 15;
    int quad = l >> 4;

    int P = KW >> 1;
    int hoff = 8 - P;
    f32x4 acc[4][4] = {};

    stageA128(Arow0, 0, As2[0], tid, w);
    stageB128(BT, Ktot, 0, Bs[0], tid);
    __syncthreads();

    int nIt = KW * 8;
    int it = 0;
    for (int c = 0; c < 8; ++c) {
        for (int tap = 0; tap < KW; ++tap, ++it) {
            if (tap == 0 && c < 7)
                stageA128(Arow0, c + 1, As2[(c + 1) & 1], tid, w);
            if (it + 1 < nIt) {
                int tapn = tap + 1, cn = c;
                if (tapn == KW) { tapn = 0; cn = c + 1; }
                stageB128(BT, Ktot, tapn * 256 + cn * 32, Bs[(it + 1) & 1], tid);
            }
            const ushort_t* asb = As2[c & 1];
            const ushort_t* bsb = Bs[it & 1];
            bf16x8 av[4], bv[4];
            #pragma unroll
            for (int m = 0; m < 4; ++m) {
                int row = wr * 64 + m * 16 + lr + tap + hoff;
                int cs = quad ^ ((row >> 1) & 3);
                av[m] = *reinterpret_cast<const bf16x8*>(&asb[row * 32 + cs * 8]);
            }
            #pragma unroll
            for (int n = 0; n < 4; ++n) {
                int nn = wc * 64 + n * 16 + lr;
                int cs = quad ^ ((nn >> 1) & 3);
                bv[n] = *reinterpret_cast<const bf16x8*>(&bsb[nn * 32 + cs * 8]);
            }
            #pragma unroll
            for (int m = 0; m < 4; ++m)
                #pragma unroll
                for (int n = 0; n < 4; ++n)
                    acc[m][n] = __builtin_amdgcn_mfma_f32_16x16x32_bf16(av[m], bv[n], acc[m][n], 0, 0, 0);
            __syncthreads();
        }
    }

    // ---- epilogue: bias + GELU + LN + bf16 write (stats overlay Bs[0]) ----
    float* rs = (float*)&Bs[0][0];      // [128][4]
    float* rq = rs + 512;               // [128][4]
    float bias_c[4], lng_c[4], lnb_c[4];
    #pragma unroll
    for (int n = 0; n < 4; ++n) {
        int col = wc * 64 + n * 16 + lr;
        bias_c[n] = bias[col];
        lng_c[n] = lng[col];
        lnb_c[n] = lnb[col];
    }
    #pragma unroll
    for (int m = 0; m < 4; ++m) {
        #pragma unroll
        for (int r = 0; r < 4; ++r) {
            float s = 0.0f, sq = 0.0f;
            #pragma unroll
            for (int n = 0; n < 4; ++n) {
                float v = acc[m][n][r] + bias_c[n];
                v = gelu_exact(v);
                acc[m][n][r] = v;
                s += v; sq += v * v;
            }
            s += __shfl_xor(s, 1);  sq += __shfl_xor(sq, 1);
            s += __shfl_xor(s, 2);  sq += __shfl_xor(sq, 2);
            s += __shfl_xor(s, 4);  sq += __shfl_xor(sq, 4);
            s += __shfl_xor(s, 8);  sq += __shfl_xor(sq, 8);
            if (lr == 0) {
                int rl = wr * 64 + m * 16 + quad * 4 + r;
                rs[rl * 4 + wc] = s;
                rq[rl * 4 + wc] = sq;
            }
        }
    }
    __syncthreads();
    #pragma unroll
    for (int m = 0; m < 4; ++m) {
        #pragma unroll
        for (int r = 0; r < 4; ++r) {
            int rl = wr * 64 + m * 16 + quad * 4 + r;
            float mean = (rs[rl * 4] + rs[rl * 4 + 1] + rs[rl * 4 + 2] + rs[rl * 4 + 3]) * (1.0f / 256.0f);
            float var = (rq[rl * 4] + rq[rl * 4 + 1] + rq[rl * 4 + 2] + rq[rl * 4 + 3]) * (1.0f / 256.0f) - mean * mean;
            float inv = rsqrtf(var + 1e-3f);
            int trow = tloc + rl;
            ushort_t* cp = ctx_out + ((size_t)b * PADROWS + PAD0 + trow) * CDIM;
            #pragma unroll
            for (int n = 0; n < 4; ++n) {
                int col = wc * 64 + n * 16 + lr;
                float y = (acc[m][n][r] - mean) * inv * lng_c[n] + lnb_c[n];
                cp[col] = f2bf(y);
            }
        }
    }
}

// ---------------- column mean over L (two stage), input bf16 padded ----------------
__global__ __launch_bounds__(256) void col_mean_partial(const ushort_t* __restrict__ ctx_pad,
                                                        float* __restrict__ partial) {
    int b = blockIdx.x, chunk = blockIdx.y, c = threadIdx.x;
    const ushort_t* base = ctx_pad + ((size_t)b * PADROWS + PAD0 + chunk * 256) * CDIM + c;
    float s = 0.0f;
    for (int r = 0; r < 256; ++r) s += bf2f(base[(size_t)r * CDIM]);
    partial[((size_t)b * 32 + chunk) * CDIM + c] = s;
}

__global__ __launch_bounds__(256) void col_mean_final(const float* __restrict__ partial,
                                                      float* __restrict__ meanv) {
    int b = blockIdx.x, c = threadIdx.x;
    float s = 0.0f;
    for (int i = 0; i < 32; ++i) s += partial[((size_t)b * 32 + i) * CDIM + c];
    meanv[b * CDIM + c] = s * (1.0f / (float)LSEQ);
}

// ---------------- A_bf = bf16(sum_l gate_l*ctx_l + meanv*g3) ----------------
__global__ __launch_bounds__(256) void finalize_A(
    const ushort_t* __restrict__ c0buf, const ushort_t* __restrict__ c1buf,
    const ushort_t* __restrict__ c2buf,
    const float* __restrict__ meanv, const float* __restrict__ gates,
    ushort_t* __restrict__ A_bf)
{
    int i = blockIdx.x * 256 + threadIdx.x;   // 8 channels per thread
    int t = i >> 5;
    int c8 = (i & 31) * 8;
    int b = t >> 13, tb = t & (LSEQ - 1);
    size_t pidx = ((size_t)b * PADROWS + PAD0 + tb) * CDIM + c8;
    const float* g = gates + (size_t)t * 4;
    float g0 = g[0], g1 = g[1], g2 = g[2], g3 = g[3];
    ushort4 a0 = *(const ushort4*)(c0buf + pidx);
    ushort4 a1 = *(const ushort4*)(c0buf + pidx + 4);
    ushort4 b0 = *(const ushort4*)(c1buf + pidx);
    ushort4 b1 = *(const ushort4*)(c1buf + pidx + 4);
    ushort4 d0 = *(const ushort4*)(c2buf + pidx);
    ushort4 d1 = *(const ushort4*)(c2buf + pidx + 4);
    const float* mv = meanv + b * CDIM + c8;
    ushort_t out[8];
    ushort_t va[8] = { a0.x, a0.y, a0.z, a0.w, a1.x, a1.y, a1.z, a1.w };
    ushort_t vb[8] = { b0.x, b0.y, b0.z, b0.w, b1.x, b1.y, b1.z, b1.w };
    ushort_t vd[8] = { d0.x, d0.y, d0.z, d0.w, d1.x, d1.y, d1.z, d1.w };
    #pragma unroll
    for (int j = 0; j < 8; ++j) {
        float v = bf2f(va[j]) * g0 + bf2f(vb[j]) * g1 + bf2f(vd[j]) * g2 + mv[j] * g3;
        out[j] = f2bf(v);
    }
    *(ushort4*)(A_bf + (size_t)t * CDIM + c8)     = make_ushort4(out[0], out[1], out[2], out[3]);
    *(ushort4*)(A_bf + (size_t)t * CDIM + c8 + 4) = make_ushort4(out[4], out[5], out[6], out[7]);
}

extern "C" void kernel_launch(void* const* d_in, const int* in_sizes, int n_in,
                              void* d_out, int out_size, void* d_ws, size_t ws_size,
                              hipStream_t stream) {
    const float* x      = (const float*)d_in[0];
    const float* f_w    = (const float*)d_in[1];
    const float* f_b    = (const float*)d_in[2];
    const float* h_w    = (const float*)d_in[3];
    const float* h_b    = (const float*)d_in[4];
    const float* proj_w = (const float*)d_in[5];
    const float* proj_b = (const float*)d_in[6];
    const float* conv_w[3] = { (const float*)d_in[7],  (const float*)d_in[11], (const float*)d_in[15] };
    const float* conv_b[3] = { (const float*)d_in[8],  (const float*)d_in[12], (const float*)d_in[16] };
    const float* ln_g[3]   = { (const float*)d_in[9],  (const float*)d_in[13], (const float*)d_in[17] };
    const float* ln_b[3]   = { (const float*)d_in[10], (const float*)d_in[14], (const float*)d_in[18] };

    const size_t MC = (size_t)MTOT * CDIM;
    const size_t PADC = (size_t)BATCH * PADROWS * CDIM;
    char* w = (char*)d_ws;
    ushort_t* x_bf  = (ushort_t*)w;  w += MC * 2;
    ushort_t* q_bf  = (ushort_t*)w;  w += MC * 2;
    ushort_t* ctxF  = (ushort_t*)w;  w += PADC * 2;   // ctxF..ctx2 contiguous
    ushort_t* ctx0  = (ushort_t*)w;  w += PADC * 2;
    ushort_t* ctx1  = (ushort_t*)w;  w += PADC * 2;
    ushort_t* ctx2  = (ushort_t*)w;  w += PADC * 2;
    float* gates    = (float*)w;     w += (size_t)MTOT * 4 * 4;
    float* partial  = (float*)w;     w += (size_t)8 * 32 * CDIM * 4;
    float* meanv    = (float*)w;     w += (size_t)8 * CDIM * 4;
    ushort_t* f_wT  = (ushort_t*)w;  w += (size_t)512 * 256 * 2;
    ushort_t* convT0 = (ushort_t*)w; w += (size_t)768 * 256 * 2;
    ushort_t* convT1 = (ushort_t*)w; w += (size_t)1280 * 256 * 2;
    ushort_t* convT2 = (ushort_t*)w; w += (size_t)1792 * 256 * 2;
    ushort_t* h_wT   = (ushort_t*)w; w += (size_t)256 * 256 * 2;
    ushort_t* proj_wT = (ushort_t*)w; w += (size_t)256 * 256 * 2;
    ushort_t* A_bf = x_bf;           // reuse (x_bf consumed after fea gemm)

    dim3 blk(256);

    // fused x conversion + gates; single-launch weight prep; single guard zero
    cvt_gates<<<dim3(MTOT / 4), blk, 0, stream>>>(x, f_w, f_b, x_bf, gates);
    prep_weights<<<dim3(1216), blk, 0, stream>>>(f_w, conv_w[0], conv_w[1], conv_w[2],
        h_w, proj_w, f_wT, convT0, convT1, convT2, h_wT, proj_wT);
    zero_guards_all<<<dim3(512), blk, 0, stream>>>(ctxF);

    // feature GEMM (q + ctx)
    gemm_bf16<1><<<dim3(4, 512), blk, 0, stream>>>(x_bf, f_wT, f_b,
        nullptr, q_bf, ctxF, 256);

    // three fused conv+GELU+LN levels (best verified structure)
    conv_fused<<<dim3(512), dim3(512), 0, stream>>>(ctxF, convT0, conv_b[0],
        ln_g[0], ln_b[0], ctx0, 3, 768);
    conv_fused<<<dim3(512), dim3(512), 0, stream>>>(ctx0, convT1, conv_b[1],
        ln_g[1], ln_b[1], ctx1, 5, 1280);
    conv_fused<<<dim3(512), dim3(512), 0, stream>>>(ctx1, convT2, conv_b[2],
        ln_g[2], ln_b[2], ctx2, 7, 1792);

    // global context mean (final ctx is ctx2)
    col_mean_partial<<<dim3(BATCH, 32), blk, 0, stream>>>(ctx2, partial);
    col_mean_final<<<dim3(BATCH), blk, 0, stream>>>(partial, meanv);

    // combine levels: A_bf = bf16(sum gate_l*ctx_l + mean*g3)
    finalize_A<<<dim3(MTOT * 32 / 256), blk, 0, stream>>>(ctx0, ctx1, ctx2,
        meanv, gates, A_bf);

    // h GEMM with fused q .* (.) epilogue: q_bf <- bf16(q_bf * ctxh)
    gemm_bf16<2><<<dim3(2, 512), blk, 0, stream>>>(A_bf, h_wT, h_b,
        nullptr, q_bf, nullptr, 256);
    // final projection: qc @ proj_w -> d_out (fp32)
    gemm_bf16<0><<<dim3(2, 512), blk, 0, stream>>>(q_bf, proj_wT, proj_b,
        (float*)d_out, nullptr, nullptr, 256);
}